// Round 1
// 4171.083 us; speedup vs baseline: 1.0711x; 1.0711x over previous
//
#include <hip/hip_runtime.h>
#include <hip/hip_bf16.h>

#define T_STEPS 2048
#define HDIM 256
#define VOUT 32000

typedef short short8 __attribute__((ext_vector_type(8)));
typedef float f32x4 __attribute__((ext_vector_type(4)));

// ---------- int8 dot4 (signed) with fallback ----------
#if defined(__has_builtin)
#if __has_builtin(__builtin_amdgcn_sdot4)
#define HAVE_SDOT4 1
#endif
#if __has_builtin(__builtin_amdgcn_mov_dpp)
#define HAVE_DPP 1
#endif
#endif

__device__ __forceinline__ int dot4i8(int a, int b, int c) {
#ifdef HAVE_SDOT4
    return __builtin_amdgcn_sdot4(a, b, c, false);
#else
#pragma unroll
    for (int k = 0; k < 4; ++k) {
        int av = (a << (24 - 8 * k)) >> 24;
        int bv = (b << (24 - 8 * k)) >> 24;
        c += av * bv;
    }
    return c;
#endif
}

// pair-sum across lane^1 via DPP quad_perm [1,0,3,2] (pure VALU, no LDS pipe)
__device__ __forceinline__ int pairsum(int x) {
#ifdef HAVE_DPP
    return x + __builtin_amdgcn_mov_dpp(x, 0xB1, 0xF, 0xF, true);
#else
    return x + __shfl_xor(x, 1);
#endif
}

__device__ __forceinline__ float fast_sigmoid(float x) {
    return 1.0f / (1.0f + __expf(-x));
}
__device__ __forceinline__ float fast_tanh(float x) {
    float ax = fabsf(x);
    float e = __expf(-2.0f * ax);
    float t = 1.0f - 2.0f * e / (1.0f + e);
    return copysignf(t, x);
}

// ---------- quantize a 768x256 fp32 matrix to int8 (per-row scale) ----------
__global__ void k_quant(const float* __restrict__ W, int* __restrict__ wq,
                        float* __restrict__ sc) {
    int row = blockIdx.x;
    int t = threadIdx.x;
    float4 w = ((const float4*)(W + (size_t)row * HDIM))[t];
    float m = fmaxf(fmaxf(fabsf(w.x), fabsf(w.y)), fmaxf(fabsf(w.z), fabsf(w.w)));
#pragma unroll
    for (int off = 32; off; off >>= 1) m = fmaxf(m, __shfl_xor(m, off));
    float inv = (m > 0.0f) ? 127.0f / m : 0.0f;
    float scale = (m > 0.0f) ? m * (1.0f / 127.0f) : 0.0f;
    int q0 = __float2int_rn(w.x * inv); q0 = max(-127, min(127, q0));
    int q1 = __float2int_rn(w.y * inv); q1 = max(-127, min(127, q1));
    int q2 = __float2int_rn(w.z * inv); q2 = max(-127, min(127, q2));
    int q3 = __float2int_rn(w.w * inv); q3 = max(-127, min(127, q3));
    int packed = (q0 & 255) | ((q1 & 255) << 8) | ((q2 & 255) << 16) | ((q3 & 255) << 24);
    wq[row * 64 + t] = packed;
    if (t == 0) sc[row] = scale;
}

// ---------- fp32 -> bf16 (RNE, manual to keep ushort storage) ----------
__global__ __launch_bounds__(256) void k_cvt(const float* __restrict__ in,
                                             unsigned short* __restrict__ out, int n4) {
    int i = blockIdx.x * 256 + threadIdx.x;
    if (i < n4) {
        float4 v = ((const float4*)in)[i];
        unsigned int u[4] = {__float_as_uint(v.x), __float_as_uint(v.y),
                             __float_as_uint(v.z), __float_as_uint(v.w)};
        ushort4 o;
        o.x = (unsigned short)((u[0] + 0x7FFFu + ((u[0] >> 16) & 1)) >> 16);
        o.y = (unsigned short)((u[1] + 0x7FFFu + ((u[1] >> 16) & 1)) >> 16);
        o.z = (unsigned short)((u[2] + 0x7FFFu + ((u[2] >> 16) & 1)) >> 16);
        o.w = (unsigned short)((u[3] + 0x7FFFu + ((u[3] >> 16) & 1)) >> 16);
        ((ushort4*)out)[i] = o;
    }
}

// ---------- Phase A: gi[t][row] = W_ih @ x_t + b_ih ----------
__global__ __launch_bounds__(256) void k_gi(const int* __restrict__ toks,
                                            const float* __restrict__ emb,
                                            const float* __restrict__ W,
                                            const float* __restrict__ b,
                                            float* __restrict__ gi, int do_relu) {
    __shared__ float4 xs[64];
    int t = blockIdx.x;
    int tid = threadIdx.x;
    int tok = toks[t];
    if (tid < 64) {
        float4 x = ((const float4*)(emb + (size_t)tok * HDIM))[tid];
        if (do_relu) {
            x.x = fmaxf(x.x, 0.0f); x.y = fmaxf(x.y, 0.0f);
            x.z = fmaxf(x.z, 0.0f); x.w = fmaxf(x.w, 0.0f);
        }
        xs[tid] = x;
    }
    __syncthreads();
#pragma unroll
    for (int g = 0; g < 3; ++g) {
        int row = tid + g * 256;
        const float4* wr = (const float4*)(W + (size_t)row * HDIM);
        float acc = b[row];
#pragma unroll 16
        for (int k = 0; k < 64; ++k) {
            float4 w = wr[k];
            float4 x = xs[k];
            acc += w.x * x.x + w.y * x.y + w.z * x.z + w.w * x.w;
        }
        gi[(size_t)t * 768 + row] = acc;
    }
}

// ---------- Phase B: sequential double-GRU ----------
// 512 threads = 8 waves (2/SIMD, 256 arch-VGPR budget so weights stay in VGPRs,
// no v_accvgpr_read tax). Lane: element rg = tid>>1, K-chunk c = tid&1.
// Lane holds FULL rows rg, rg+256, rg+512 of both W_hh over its 128-elem chunk
// (3*32 dwords * 2 matrices = 192 VGPRs). Gates reduce across the lane pair via
// DPP; epilogue is fully in-lane (no Y[] LDS round trip). HQ double-buffered ->
// ONE barrier per half-step (2/step vs previous 4/step).
__global__ __launch_bounds__(512, 2) void k_gru(
    const int* __restrict__ wq_e, const float* __restrict__ sc_e,
    const float* __restrict__ bhh_e, const float* __restrict__ gi_e,
    const int* __restrict__ wq_d, const float* __restrict__ sc_d,
    const float* __restrict__ bhh_d, const float* __restrict__ gi_d,
    unsigned short* __restrict__ h_bf) {
    __shared__ __align__(16) int HQ[2][64];  // 2 x 256 int8-quantized h values

    const int tid = threadIdx.x;
    const int rg = tid >> 1;  // output element [0,256)
    const int c  = tid & 1;   // K-chunk: h elements [c*128, c*128+128)

    int we[3][32], wd[3][32];
    float se[3], sd[3], be[3], bd[3];
#pragma unroll
    for (int j = 0; j < 3; ++j) {
        const int row = rg + j * 256;
        const int4* pe = (const int4*)(wq_e + (row * 64 + c * 32));
        const int4* pd = (const int4*)(wq_d + (row * 64 + c * 32));
#pragma unroll
        for (int i = 0; i < 8; ++i) {
            int4 a = pe[i];
            we[j][4 * i + 0] = a.x; we[j][4 * i + 1] = a.y;
            we[j][4 * i + 2] = a.z; we[j][4 * i + 3] = a.w;
            int4 bq = pd[i];
            wd[j][4 * i + 0] = bq.x; wd[j][4 * i + 1] = bq.y;
            wd[j][4 * i + 2] = bq.z; wd[j][4 * i + 3] = bq.w;
        }
        se[j] = sc_e[row] * (1.0f / 127.0f);
        sd[j] = sc_d[row] * (1.0f / 127.0f);
        be[j] = bhh_e[row];
        bd[j] = bhh_d[row];
    }

    float h = 0.0f;
    if (tid < 64) HQ[0][tid] = 0;
    __syncthreads();

    const float* ge = gi_e + rg;
    const float* gd = gi_d + rg;
    unsigned short* hop = h_bf + rg;
    int cur = 0;

    for (int t = 0; t < T_STEPS; ++t) {
        // ---- encoder half ----
        {
            float g0 = ge[0], g1 = ge[256], g2 = ge[512]; ge += 768;
            const int4* hq4 = ((const int4*)HQ[cur]) + c * 8;
            int p0 = 0, p1 = 0, p2 = 0;
#pragma unroll
            for (int i = 0; i < 8; ++i) {
                int4 v = hq4[i];
                p0 = dot4i8(we[0][4 * i + 0], v.x, p0);
                p1 = dot4i8(we[1][4 * i + 0], v.x, p1);
                p2 = dot4i8(we[2][4 * i + 0], v.x, p2);
                p0 = dot4i8(we[0][4 * i + 1], v.y, p0);
                p1 = dot4i8(we[1][4 * i + 1], v.y, p1);
                p2 = dot4i8(we[2][4 * i + 1], v.y, p2);
                p0 = dot4i8(we[0][4 * i + 2], v.z, p0);
                p1 = dot4i8(we[1][4 * i + 2], v.z, p1);
                p2 = dot4i8(we[2][4 * i + 2], v.z, p2);
                p0 = dot4i8(we[0][4 * i + 3], v.w, p0);
                p1 = dot4i8(we[1][4 * i + 3], v.w, p1);
                p2 = dot4i8(we[2][4 * i + 3], v.w, p2);
            }
            int f0 = pairsum(p0), f1 = pairsum(p1), f2 = pairsum(p2);
            float r = fast_sigmoid(g0 + se[0] * (float)f0 + be[0]);
            float z = fast_sigmoid(g1 + se[1] * (float)f1 + be[1]);
            float n = fast_tanh(g2 + r * (se[2] * (float)f2 + be[2]));
            h = (1.0f - z) * n + z * h;
            if (c == 0)
                ((signed char*)HQ[cur ^ 1])[rg] = (signed char)__float2int_rn(h * 127.0f);
        }
        __syncthreads();
        cur ^= 1;

        // ---- decoder half ----
        {
            float g0 = gd[0], g1 = gd[256], g2 = gd[512]; gd += 768;
            const int4* hq4 = ((const int4*)HQ[cur]) + c * 8;
            int p0 = 0, p1 = 0, p2 = 0;
#pragma unroll
            for (int i = 0; i < 8; ++i) {
                int4 v = hq4[i];
                p0 = dot4i8(wd[0][4 * i + 0], v.x, p0);
                p1 = dot4i8(wd[1][4 * i + 0], v.x, p1);
                p2 = dot4i8(wd[2][4 * i + 0], v.x, p2);
                p0 = dot4i8(wd[0][4 * i + 1], v.y, p0);
                p1 = dot4i8(wd[1][4 * i + 1], v.y, p1);
                p2 = dot4i8(wd[2][4 * i + 1], v.y, p2);
                p0 = dot4i8(wd[0][4 * i + 2], v.z, p0);
                p1 = dot4i8(wd[1][4 * i + 2], v.z, p1);
                p2 = dot4i8(wd[2][4 * i + 2], v.z, p2);
                p0 = dot4i8(wd[0][4 * i + 3], v.w, p0);
                p1 = dot4i8(wd[1][4 * i + 3], v.w, p1);
                p2 = dot4i8(wd[2][4 * i + 3], v.w, p2);
            }
            int f0 = pairsum(p0), f1 = pairsum(p1), f2 = pairsum(p2);
            float r = fast_sigmoid(g0 + sd[0] * (float)f0 + bd[0]);
            float z = fast_sigmoid(g1 + sd[1] * (float)f1 + bd[1]);
            float n = fast_tanh(g2 + r * (sd[2] * (float)f2 + bd[2]));
            h = (1.0f - z) * n + z * h;
            if (c == 0) {
                ((signed char*)HQ[cur ^ 1])[rg] = (signed char)__float2int_rn(h * 127.0f);
                unsigned int u = __float_as_uint(h);
                *hop = (unsigned short)((u + 0x7FFFu + ((u >> 16) & 1)) >> 16);
            }
            hop += 256;
        }
        __syncthreads();
        cur ^= 1;
    }
}

// ---------- Phase C1: logits = H(2048x256) @ out_W^T + b via bf16 MFMA ----------
__global__ __launch_bounds__(256) void k_logits(const unsigned short* __restrict__ hb,
                                                const unsigned short* __restrict__ wb,
                                                const float* __restrict__ out_b,
                                                float* __restrict__ out) {
    const int vb = blockIdx.x * 64;
    const int tb = blockIdx.y * 64;
    const int w = threadIdx.x >> 6;
    const int l = threadIdx.x & 63;
    const int m = l & 15;
    const int q = l >> 4;

    const unsigned short* aptr = hb + (size_t)(tb + w * 16 + m) * HDIM + q * 8;
    const unsigned short* bptr = wb + (size_t)(vb + m) * HDIM + q * 8;

    short8 af[8];
#pragma unroll
    for (int kt = 0; kt < 8; ++kt) af[kt] = *(const short8*)(aptr + kt * 32);

    f32x4 acc[4];
#pragma unroll
    for (int nt = 0; nt < 4; ++nt)
#pragma unroll
        for (int r = 0; r < 4; ++r) acc[nt][r] = 0.0f;

#pragma unroll
    for (int nt = 0; nt < 4; ++nt) {
        const unsigned short* bp = bptr + (size_t)nt * 16 * HDIM;
#pragma unroll
        for (int kt = 0; kt < 8; ++kt) {
            short8 bf = *(const short8*)(bp + kt * 32);
            acc[nt] = __builtin_amdgcn_mfma_f32_16x16x32_bf16(af[kt], bf, acc[nt], 0, 0, 0);
        }
    }
#pragma unroll
    for (int nt = 0; nt < 4; ++nt) {
        float bias = out_b[vb + nt * 16 + m];
#pragma unroll
        for (int r = 0; r < 4; ++r) {
            out[(size_t)(tb + w * 16 + q * 4 + r) * VOUT + vb + nt * 16 + m] =
                acc[nt][r] + bias;
        }
    }
}

// ---------- Phase C2: per-row logsumexp ----------
__global__ __launch_bounds__(256) void k_lse(const float* __restrict__ out,
                                             float* __restrict__ lse) {
    const int t = blockIdx.x;
    const int tid = threadIdx.x;
    const float* rowp = out + (size_t)t * VOUT;
    float m = -3.0e38f, l = 0.0f;
    for (int v = tid; v < VOUT; v += 256) {
        float x = rowp[v];
        float M = fmaxf(m, x);
        l = l * __expf(m - M) + __expf(x - M);
        m = M;
    }
#pragma unroll
    for (int off = 32; off; off >>= 1) {
        float m2 = __shfl_xor(m, off);
        float l2 = __shfl_xor(l, off);
        float M = fmaxf(m, m2);
        l = l * __expf(m - M) + l2 * __expf(m2 - M);
        m = M;
    }
    __shared__ float sm[4], sl[4];
    int lane = tid & 63, wv = tid >> 6;
    if (lane == 0) { sm[wv] = m; sl[wv] = l; }
    __syncthreads();
    if (tid == 0) {
        float M = fmaxf(fmaxf(sm[0], sm[1]), fmaxf(sm[2], sm[3]));
        float L = sl[0] * __expf(sm[0] - M) + sl[1] * __expf(sm[1] - M) +
                  sl[2] * __expf(sm[2] - M) + sl[3] * __expf(sm[3] - M);
        lse[t] = M + __logf(L);
    }
}

// ---------- Phase C3: out -= lse[t] ----------
__global__ __launch_bounds__(256) void k_sub(float* __restrict__ out,
                                             const float* __restrict__ lse) {
    const int t = blockIdx.y;
    const int v4 = blockIdx.x * 256 + threadIdx.x;
    if (v4 < VOUT / 4) {
        float s = lse[t];
        float4* p = (float4*)(out + (size_t)t * VOUT) + v4;
        float4 o = *p;
        o.x -= s; o.y -= s; o.z -= s; o.w -= s;
        *p = o;
    }
}

extern "C" void kernel_launch(void* const* d_in, const int* in_sizes, int n_in,
                              void* d_out, int out_size, void* d_ws, size_t ws_size,
                              hipStream_t stream) {
    (void)in_sizes; (void)n_in; (void)out_size; (void)ws_size;
    const int*   src      = (const int*)d_in[0];
    const int*   trg      = (const int*)d_in[1];
    const float* enc_emb  = (const float*)d_in[2];
    const float* enc_W_ih = (const float*)d_in[3];
    const float* enc_W_hh = (const float*)d_in[4];
    const float* enc_b_ih = (const float*)d_in[5];
    const float* enc_b_hh = (const float*)d_in[6];
    const float* dec_emb  = (const float*)d_in[7];
    const float* dec_W_ih = (const float*)d_in[8];
    const float* dec_W_hh = (const float*)d_in[9];
    const float* dec_b_ih = (const float*)d_in[10];
    const float* dec_b_hh = (const float*)d_in[11];
    const float* out_W    = (const float*)d_in[12];
    const float* out_b    = (const float*)d_in[13];
    float* out = (float*)d_out;

    char* ws = (char*)d_ws;
    float* gi_e  = (float*)ws; ws += (size_t)T_STEPS * 768 * 4;
    float* gi_d  = (float*)ws; ws += (size_t)T_STEPS * 768 * 4;
    float* lse   = (float*)ws; ws += (size_t)T_STEPS * 4;
    float* sc_e  = (float*)ws; ws += 768 * 4;
    float* sc_d  = (float*)ws; ws += 768 * 4;
    int*   wq_e  = (int*)ws;   ws += 768 * 64 * 4;
    int*   wq_d  = (int*)ws;   ws += 768 * 64 * 4;
    unsigned short* h_bf = (unsigned short*)ws; ws += (size_t)T_STEPS * HDIM * 2;
    unsigned short* w_bf = (unsigned short*)ws; ws += (size_t)VOUT * HDIM * 2;

    k_quant<<<768, 64, 0, stream>>>(enc_W_hh, wq_e, sc_e);
    k_quant<<<768, 64, 0, stream>>>(dec_W_hh, wq_d, sc_d);
    k_cvt<<<(VOUT * HDIM / 4 + 255) / 256, 256, 0, stream>>>(out_W, w_bf, VOUT * HDIM / 4);
    k_gi<<<T_STEPS, 256, 0, stream>>>(src, enc_emb, enc_W_ih, enc_b_ih, gi_e, 0);
    k_gi<<<T_STEPS, 256, 0, stream>>>(trg, dec_emb, dec_W_ih, dec_b_ih, gi_d, 1);
    k_gru<<<1, 512, 0, stream>>>(wq_e, sc_e, enc_b_hh, gi_e,
                                 wq_d, sc_d, dec_b_hh, gi_d, h_bf);
    k_logits<<<dim3(VOUT / 64, T_STEPS / 64), 256, 0, stream>>>(h_bf, w_bf, out_b, out);
    k_lse<<<T_STEPS, 256, 0, stream>>>(out, lse);
    k_sub<<<dim3(32, T_STEPS), 256, 0, stream>>>(out, lse);
}

// Round 3
// 3783.183 us; speedup vs baseline: 1.1809x; 1.1025x over previous
//
#include <hip/hip_runtime.h>
#include <hip/hip_bf16.h>

#define T_STEPS 2048
#define HDIM 256
#define VOUT 32000

typedef short short8 __attribute__((ext_vector_type(8)));
typedef float f32x4 __attribute__((ext_vector_type(4)));

// ---------- builtins with fallback ----------
#if defined(__has_builtin)
#if __has_builtin(__builtin_amdgcn_sdot4)
#define HAVE_SDOT4 1
#endif
#if __has_builtin(__builtin_amdgcn_mov_dpp)
#define HAVE_DPP 1
#endif
#if __has_builtin(__builtin_amdgcn_rcpf)
#define HAVE_RCP 1
#endif
#endif

__device__ __forceinline__ int dot4i8(int a, int b, int c) {
#ifdef HAVE_SDOT4
    return __builtin_amdgcn_sdot4(a, b, c, false);
#else
#pragma unroll
    for (int k = 0; k < 4; ++k) {
        int av = (a << (24 - 8 * k)) >> 24;
        int bv = (b << (24 - 8 * k)) >> 24;
        c += av * bv;
    }
    return c;
#endif
}

// pair-sum across lane^1 via DPP quad_perm [1,0,3,2] (pure VALU, no LDS pipe)
__device__ __forceinline__ int pairsum(int x) {
#ifdef HAVE_DPP
    return x + __builtin_amdgcn_mov_dpp(x, 0xB1, 0xF, 0xF, true);
#else
    return x + __shfl_xor(x, 1);
#endif
}

__device__ __forceinline__ float fast_rcp(float x) {
#ifdef HAVE_RCP
    return __builtin_amdgcn_rcpf(x);
#else
    return 1.0f / x;
#endif
}

__device__ __forceinline__ float fast_sigmoid(float x) {
    return fast_rcp(1.0f + __expf(-x));
}
__device__ __forceinline__ float fast_tanh(float x) {
    float ax = fabsf(x);
    float e = __expf(-2.0f * ax);
    float t = 1.0f - 2.0f * e * fast_rcp(1.0f + e);
    return copysignf(t, x);
}

// ---------- quantize a 768x256 fp32 matrix to int8 (per-row scale) ----------
__global__ void k_quant(const float* __restrict__ W, int* __restrict__ wq,
                        float* __restrict__ sc) {
    int row = blockIdx.x;
    int t = threadIdx.x;
    float4 w = ((const float4*)(W + (size_t)row * HDIM))[t];
    float m = fmaxf(fmaxf(fabsf(w.x), fabsf(w.y)), fmaxf(fabsf(w.z), fabsf(w.w)));
#pragma unroll
    for (int off = 32; off; off >>= 1) m = fmaxf(m, __shfl_xor(m, off));
    float inv = (m > 0.0f) ? 127.0f / m : 0.0f;
    float scale = (m > 0.0f) ? m * (1.0f / 127.0f) : 0.0f;
    int q0 = __float2int_rn(w.x * inv); q0 = max(-127, min(127, q0));
    int q1 = __float2int_rn(w.y * inv); q1 = max(-127, min(127, q1));
    int q2 = __float2int_rn(w.z * inv); q2 = max(-127, min(127, q2));
    int q3 = __float2int_rn(w.w * inv); q3 = max(-127, min(127, q3));
    int packed = (q0 & 255) | ((q1 & 255) << 8) | ((q2 & 255) << 16) | ((q3 & 255) << 24);
    wq[row * 64 + t] = packed;
    if (t == 0) sc[row] = scale;
}

// ---------- fp32 -> bf16 (RNE, manual to keep ushort storage) ----------
__global__ __launch_bounds__(256) void k_cvt(const float* __restrict__ in,
                                             unsigned short* __restrict__ out, int n4) {
    int i = blockIdx.x * 256 + threadIdx.x;
    if (i < n4) {
        float4 v = ((const float4*)in)[i];
        unsigned int u[4] = {__float_as_uint(v.x), __float_as_uint(v.y),
                             __float_as_uint(v.z), __float_as_uint(v.w)};
        ushort4 o;
        o.x = (unsigned short)((u[0] + 0x7FFFu + ((u[0] >> 16) & 1)) >> 16);
        o.y = (unsigned short)((u[1] + 0x7FFFu + ((u[1] >> 16) & 1)) >> 16);
        o.z = (unsigned short)((u[2] + 0x7FFFu + ((u[2] >> 16) & 1)) >> 16);
        o.w = (unsigned short)((u[3] + 0x7FFFu + ((u[3] >> 16) & 1)) >> 16);
        ((ushort4*)out)[i] = o;
    }
}

// ---------- Phase A: gi[t][row] = W_ih @ x_t + b_ih ----------
__global__ __launch_bounds__(256) void k_gi(const int* __restrict__ toks,
                                            const float* __restrict__ emb,
                                            const float* __restrict__ W,
                                            const float* __restrict__ b,
                                            float* __restrict__ gi, int do_relu) {
    __shared__ float4 xs[64];
    int t = blockIdx.x;
    int tid = threadIdx.x;
    int tok = toks[t];
    if (tid < 64) {
        float4 x = ((const float4*)(emb + (size_t)tok * HDIM))[tid];
        if (do_relu) {
            x.x = fmaxf(x.x, 0.0f); x.y = fmaxf(x.y, 0.0f);
            x.z = fmaxf(x.z, 0.0f); x.w = fmaxf(x.w, 0.0f);
        }
        xs[tid] = x;
    }
    __syncthreads();
#pragma unroll
    for (int g = 0; g < 3; ++g) {
        int row = tid + g * 256;
        const float4* wr = (const float4*)(W + (size_t)row * HDIM);
        float acc = b[row];
#pragma unroll 16
        for (int k = 0; k < 64; ++k) {
            float4 w = wr[k];
            float4 x = xs[k];
            acc += w.x * x.x + w.y * x.y + w.z * x.z + w.w * x.w;
        }
        gi[(size_t)t * 768 + row] = acc;
    }
}

// ---------- Phase B: sequential double-GRU ----------
// 512 threads = 8 waves. Lane: element rg = tid>>1, K-chunk c = tid&1.
// Static double-buffer: encoder reads HQA, writes HQB; decoder reads HQB,
// writes HQA. One barrier per half-step.
// gi streams are software-pipelined a half/full step ahead so L3/HBM latency
// (~400-900cy) hides under the dot+epilogue work.
__global__ __launch_bounds__(512, 2) void k_gru(
    const int* __restrict__ wq_e, const float* __restrict__ sc_e,
    const float* __restrict__ bhh_e, const float* __restrict__ gi_e,
    const int* __restrict__ wq_d, const float* __restrict__ sc_d,
    const float* __restrict__ bhh_d, const float* __restrict__ gi_d,
    unsigned short* __restrict__ h_bf) {
    __shared__ __align__(16) int HQA[64];  // input to encoder half
    __shared__ __align__(16) int HQB[64];  // input to decoder half

    const int tid = threadIdx.x;
    const int rg = tid >> 1;  // output element [0,256)
    const int c  = tid & 1;   // K-chunk: h elements [c*128, c*128+128)

    int we[3][32], wd[3][32];
    float se[3], sd[3], be[3], bd[3];
#pragma unroll
    for (int j = 0; j < 3; ++j) {
        const int row = rg + j * 256;
        const int4* pe = (const int4*)(wq_e + (row * 64 + c * 32));
        const int4* pd = (const int4*)(wq_d + (row * 64 + c * 32));
#pragma unroll
        for (int i = 0; i < 8; ++i) {
            int4 a = pe[i];
            we[j][4 * i + 0] = a.x; we[j][4 * i + 1] = a.y;
            we[j][4 * i + 2] = a.z; we[j][4 * i + 3] = a.w;
            int4 bq = pd[i];
            wd[j][4 * i + 0] = bq.x; wd[j][4 * i + 1] = bq.y;
            wd[j][4 * i + 2] = bq.z; wd[j][4 * i + 3] = bq.w;
        }
        se[j] = sc_e[row] * (1.0f / 127.0f);
        sd[j] = sc_d[row] * (1.0f / 127.0f);
        be[j] = bhh_e[row];
        bd[j] = bhh_d[row];
    }

    float h = 0.0f;
    if (tid < 64) HQA[tid] = 0;
    __syncthreads();

    const float* ge = gi_e + rg;
    const float* gd = gi_d + rg;
    unsigned short* hop = h_bf + rg;

    // prologue prefetch: encoder gi of step 0
    float eg0 = ge[0], eg1 = ge[256], eg2 = ge[512];

    for (int t = 0; t < T_STEPS; ++t) {
        // prefetch decoder gi of THIS step (consumed ~a half-step from now)
        float dg0 = gd[0], dg1 = gd[256], dg2 = gd[512];
        gd += 768;

        // ---- encoder half: HQA -> HQB ----
        {
            const int4* hq4 = ((const int4*)HQA) + c * 8;
            int p0 = 0, p1 = 0, p2 = 0;
#pragma unroll
            for (int i = 0; i < 8; ++i) {
                int4 v = hq4[i];
                p0 = dot4i8(we[0][4 * i + 0], v.x, p0);
                p1 = dot4i8(we[1][4 * i + 0], v.x, p1);
                p2 = dot4i8(we[2][4 * i + 0], v.x, p2);
                p0 = dot4i8(we[0][4 * i + 1], v.y, p0);
                p1 = dot4i8(we[1][4 * i + 1], v.y, p1);
                p2 = dot4i8(we[2][4 * i + 1], v.y, p2);
                p0 = dot4i8(we[0][4 * i + 2], v.z, p0);
                p1 = dot4i8(we[1][4 * i + 2], v.z, p1);
                p2 = dot4i8(we[2][4 * i + 2], v.z, p2);
                p0 = dot4i8(we[0][4 * i + 3], v.w, p0);
                p1 = dot4i8(we[1][4 * i + 3], v.w, p1);
                p2 = dot4i8(we[2][4 * i + 3], v.w, p2);
            }
            int f0 = pairsum(p0), f1 = pairsum(p1), f2 = pairsum(p2);
            float r = fast_sigmoid(eg0 + se[0] * (float)f0 + be[0]);
            float z = fast_sigmoid(eg1 + se[1] * (float)f1 + be[1]);
            float n = fast_tanh(eg2 + r * (se[2] * (float)f2 + be[2]));
            h = (1.0f - z) * n + z * h;
            if (c == 0)
                ((signed char*)HQB)[rg] = (signed char)__float2int_rn(h * 127.0f);
        }
        __syncthreads();

        // prefetch encoder gi of NEXT step (consumed a full step from now).
        // Last iteration: clamp back to step 0's row so the address stays
        // inside gi_e (values unused).
        {
            const float* gen = (t < T_STEPS - 1) ? (ge + 768) : (gi_e + rg);
            eg0 = gen[0]; eg1 = gen[256]; eg2 = gen[512];
            ge = gen;
        }

        // ---- decoder half: HQB -> HQA ----
        {
            const int4* hq4 = ((const int4*)HQB) + c * 8;
            int p0 = 0, p1 = 0, p2 = 0;
#pragma unroll
            for (int i = 0; i < 8; ++i) {
                int4 v = hq4[i];
                p0 = dot4i8(wd[0][4 * i + 0], v.x, p0);
                p1 = dot4i8(wd[1][4 * i + 0], v.x, p1);
                p2 = dot4i8(wd[2][4 * i + 0], v.x, p2);
                p0 = dot4i8(wd[0][4 * i + 1], v.y, p0);
                p1 = dot4i8(wd[1][4 * i + 1], v.y, p1);
                p2 = dot4i8(wd[2][4 * i + 1], v.y, p2);
                p0 = dot4i8(wd[0][4 * i + 2], v.z, p0);
                p1 = dot4i8(wd[1][4 * i + 2], v.z, p1);
                p2 = dot4i8(wd[2][4 * i + 2], v.z, p2);
                p0 = dot4i8(wd[0][4 * i + 3], v.w, p0);
                p1 = dot4i8(wd[1][4 * i + 3], v.w, p1);
                p2 = dot4i8(wd[2][4 * i + 3], v.w, p2);
            }
            int f0 = pairsum(p0), f1 = pairsum(p1), f2 = pairsum(p2);
            float r = fast_sigmoid(dg0 + sd[0] * (float)f0 + bd[0]);
            float z = fast_sigmoid(dg1 + sd[1] * (float)f1 + bd[1]);
            float n = fast_tanh(dg2 + r * (sd[2] * (float)f2 + bd[2]));
            h = (1.0f - z) * n + z * h;
            if (c == 0) {
                ((signed char*)HQA)[rg] = (signed char)__float2int_rn(h * 127.0f);
                unsigned int u = __float_as_uint(h);
                *hop = (unsigned short)((u + 0x7FFFu + ((u >> 16) & 1)) >> 16);
            }
            hop += 256;
        }
        __syncthreads();
    }
}

// ---------- Phase C1: logits = H(2048x256) @ out_W^T + b via bf16 MFMA ----------
__global__ __launch_bounds__(256) void k_logits(const unsigned short* __restrict__ hb,
                                                const unsigned short* __restrict__ wb,
                                                const float* __restrict__ out_b,
                                                float* __restrict__ out) {
    const int vb = blockIdx.x * 64;
    const int tb = blockIdx.y * 64;
    const int w = threadIdx.x >> 6;
    const int l = threadIdx.x & 63;
    const int m = l & 15;
    const int q = l >> 4;

    const unsigned short* aptr = hb + (size_t)(tb + w * 16 + m) * HDIM + q * 8;
    const unsigned short* bptr = wb + (size_t)(vb + m) * HDIM + q * 8;

    short8 af[8];
#pragma unroll
    for (int kt = 0; kt < 8; ++kt) af[kt] = *(const short8*)(aptr + kt * 32);

    f32x4 acc[4];
#pragma unroll
    for (int nt = 0; nt < 4; ++nt)
#pragma unroll
        for (int r = 0; r < 4; ++r) acc[nt][r] = 0.0f;

#pragma unroll
    for (int nt = 0; nt < 4; ++nt) {
        const unsigned short* bp = bptr + (size_t)nt * 16 * HDIM;
#pragma unroll
        for (int kt = 0; kt < 8; ++kt) {
            short8 bf = *(const short8*)(bp + kt * 32);
            acc[nt] = __builtin_amdgcn_mfma_f32_16x16x32_bf16(af[kt], bf, acc[nt], 0, 0, 0);
        }
    }
#pragma unroll
    for (int nt = 0; nt < 4; ++nt) {
        float bias = out_b[vb + nt * 16 + m];
#pragma unroll
        for (int r = 0; r < 4; ++r) {
            out[(size_t)(tb + w * 16 + q * 4 + r) * VOUT + vb + nt * 16 + m] =
                acc[nt][r] + bias;
        }
    }
}

// ---------- Phase C2+C3 fused: per-row logsumexp then subtract ----------
// One block per row; the 128KB row stays hot in this block's XCD L2 between
// the reduction pass and the subtract pass.
__global__ __launch_bounds__(256) void k_lsesub(float* __restrict__ out) {
    const int t = blockIdx.x;
    const int tid = threadIdx.x;
    float* rowp = out + (size_t)t * VOUT;
    float m = -3.0e38f, l = 0.0f;
    for (int v = tid; v < VOUT; v += 256) {
        float x = rowp[v];
        float M = fmaxf(m, x);
        l = l * __expf(m - M) + __expf(x - M);
        m = M;
    }
#pragma unroll
    for (int off = 32; off; off >>= 1) {
        float m2 = __shfl_xor(m, off);
        float l2 = __shfl_xor(l, off);
        float M = fmaxf(m, m2);
        l = l * __expf(m - M) + l2 * __expf(m2 - M);
        m = M;
    }
    __shared__ float sm[4], sl[4];
    __shared__ float s_lse;
    int lane = tid & 63, wv = tid >> 6;
    if (lane == 0) { sm[wv] = m; sl[wv] = l; }
    __syncthreads();
    if (tid == 0) {
        float M = fmaxf(fmaxf(sm[0], sm[1]), fmaxf(sm[2], sm[3]));
        float L = sl[0] * __expf(sm[0] - M) + sl[1] * __expf(sm[1] - M) +
                  sl[2] * __expf(sm[2] - M) + sl[3] * __expf(sm[3] - M);
        s_lse = M + __logf(L);
    }
    __syncthreads();
    float s = s_lse;
    float4* p4 = (float4*)rowp;
    for (int i = tid; i < VOUT / 4; i += 256) {
        float4 o = p4[i];
        o.x -= s; o.y -= s; o.z -= s; o.w -= s;
        p4[i] = o;
    }
}

extern "C" void kernel_launch(void* const* d_in, const int* in_sizes, int n_in,
                              void* d_out, int out_size, void* d_ws, size_t ws_size,
                              hipStream_t stream) {
    (void)in_sizes; (void)n_in; (void)out_size; (void)ws_size;
    const int*   src      = (const int*)d_in[0];
    const int*   trg      = (const int*)d_in[1];
    const float* enc_emb  = (const float*)d_in[2];
    const float* enc_W_ih = (const float*)d_in[3];
    const float* enc_W_hh = (const float*)d_in[4];
    const float* enc_b_ih = (const float*)d_in[5];
    const float* enc_b_hh = (const float*)d_in[6];
    const float* dec_emb  = (const float*)d_in[7];
    const float* dec_W_ih = (const float*)d_in[8];
    const float* dec_W_hh = (const float*)d_in[9];
    const float* dec_b_ih = (const float*)d_in[10];
    const float* dec_b_hh = (const float*)d_in[11];
    const float* out_W    = (const float*)d_in[12];
    const float* out_b    = (const float*)d_in[13];
    float* out = (float*)d_out;

    char* ws = (char*)d_ws;
    float* gi_e  = (float*)ws; ws += (size_t)T_STEPS * 768 * 4;
    float* gi_d  = (float*)ws; ws += (size_t)T_STEPS * 768 * 4;
    float* sc_e  = (float*)ws; ws += 768 * 4;
    float* sc_d  = (float*)ws; ws += 768 * 4;
    int*   wq_e  = (int*)ws;   ws += 768 * 64 * 4;
    int*   wq_d  = (int*)ws;   ws += 768 * 64 * 4;
    unsigned short* h_bf = (unsigned short*)ws; ws += (size_t)T_STEPS * HDIM * 2;
    unsigned short* w_bf = (unsigned short*)ws; ws += (size_t)VOUT * HDIM * 2;

    k_quant<<<768, 64, 0, stream>>>(enc_W_hh, wq_e, sc_e);
    k_quant<<<768, 64, 0, stream>>>(dec_W_hh, wq_d, sc_d);
    k_cvt<<<(VOUT * HDIM / 4 + 255) / 256, 256, 0, stream>>>(out_W, w_bf, VOUT * HDIM / 4);
    k_gi<<<T_STEPS, 256, 0, stream>>>(src, enc_emb, enc_W_ih, enc_b_ih, gi_e, 0);
    k_gi<<<T_STEPS, 256, 0, stream>>>(trg, dec_emb, dec_W_ih, dec_b_ih, gi_d, 1);
    k_gru<<<1, 512, 0, stream>>>(wq_e, sc_e, enc_b_hh, gi_e,
                                 wq_d, sc_d, dec_b_hh, gi_d, h_bf);
    k_logits<<<dim3(VOUT / 64, T_STEPS / 64), 256, 0, stream>>>(h_bf, w_bf, out_b, out);
    k_lsesub<<<T_STEPS, 256, 0, stream>>>(out);
}

// Round 4
// 3770.725 us; speedup vs baseline: 1.1848x; 1.0033x over previous
//
#include <hip/hip_runtime.h>
#include <hip/hip_bf16.h>

#define T_STEPS 2048
#define HDIM 256
#define VOUT 32000

typedef short short8 __attribute__((ext_vector_type(8)));
typedef float f32x4 __attribute__((ext_vector_type(4)));

// ---------- builtins with fallback ----------
#if defined(__has_builtin)
#if __has_builtin(__builtin_amdgcn_sdot4)
#define HAVE_SDOT4 1
#endif
#if __has_builtin(__builtin_amdgcn_mov_dpp)
#define HAVE_DPP 1
#endif
#if __has_builtin(__builtin_amdgcn_rcpf)
#define HAVE_RCP 1
#endif
#endif

__device__ __forceinline__ int dot4i8(int a, int b, int c) {
#ifdef HAVE_SDOT4
    return __builtin_amdgcn_sdot4(a, b, c, false);
#else
#pragma unroll
    for (int k = 0; k < 4; ++k) {
        int av = (a << (24 - 8 * k)) >> 24;
        int bv = (b << (24 - 8 * k)) >> 24;
        c += av * bv;
    }
    return c;
#endif
}

// keep + (send from lane^1): DPP quad_perm [1,0,3,2]
__device__ __forceinline__ int xor1_add(int keep, int send) {
#ifdef HAVE_DPP
    return keep + __builtin_amdgcn_mov_dpp(send, 0xB1, 0xF, 0xF, true);
#else
    return keep + __shfl_xor(send, 1);
#endif
}
// x + (x from lane^2): DPP quad_perm [2,3,0,1]
__device__ __forceinline__ int xor2_sum(int x) {
#ifdef HAVE_DPP
    return x + __builtin_amdgcn_mov_dpp(x, 0x4E, 0xF, 0xF, true);
#else
    return x + __shfl_xor(x, 2);
#endif
}

__device__ __forceinline__ float fast_rcp(float x) {
#ifdef HAVE_RCP
    return __builtin_amdgcn_rcpf(x);
#else
    return 1.0f / x;
#endif
}
__device__ __forceinline__ float fast_sigmoid(float x) {
    return fast_rcp(1.0f + __expf(-x));
}
__device__ __forceinline__ float fast_tanh(float x) {
    float ax = fabsf(x);
    float e = __expf(-2.0f * ax);
    float t = 1.0f - 2.0f * e * fast_rcp(1.0f + e);
    return copysignf(t, x);
}

// raw barrier: order LDS only; global loads/stores float across (no vmcnt drain)
__device__ __forceinline__ void barrier_lds() {
    asm volatile("s_waitcnt lgkmcnt(0)\n\ts_barrier" ::: "memory");
}

// ---------- quantize a 768x256 fp32 matrix to int8 (per-row scale) ----------
__global__ void k_quant(const float* __restrict__ W, int* __restrict__ wq,
                        float* __restrict__ sc) {
    int row = blockIdx.x;
    int t = threadIdx.x;
    float4 w = ((const float4*)(W + (size_t)row * HDIM))[t];
    float m = fmaxf(fmaxf(fabsf(w.x), fabsf(w.y)), fmaxf(fabsf(w.z), fabsf(w.w)));
#pragma unroll
    for (int off = 32; off; off >>= 1) m = fmaxf(m, __shfl_xor(m, off));
    float inv = (m > 0.0f) ? 127.0f / m : 0.0f;
    float scale = (m > 0.0f) ? m * (1.0f / 127.0f) : 0.0f;
    int q0 = __float2int_rn(w.x * inv); q0 = max(-127, min(127, q0));
    int q1 = __float2int_rn(w.y * inv); q1 = max(-127, min(127, q1));
    int q2 = __float2int_rn(w.z * inv); q2 = max(-127, min(127, q2));
    int q3 = __float2int_rn(w.w * inv); q3 = max(-127, min(127, q3));
    int packed = (q0 & 255) | ((q1 & 255) << 8) | ((q2 & 255) << 16) | ((q3 & 255) << 24);
    wq[row * 64 + t] = packed;
    if (t == 0) sc[row] = scale;
}

// ---------- fp32 -> bf16 (RNE, manual to keep ushort storage) ----------
__global__ __launch_bounds__(256) void k_cvt(const float* __restrict__ in,
                                             unsigned short* __restrict__ out, int n4) {
    int i = blockIdx.x * 256 + threadIdx.x;
    if (i < n4) {
        float4 v = ((const float4*)in)[i];
        unsigned int u[4] = {__float_as_uint(v.x), __float_as_uint(v.y),
                             __float_as_uint(v.z), __float_as_uint(v.w)};
        ushort4 o;
        o.x = (unsigned short)((u[0] + 0x7FFFu + ((u[0] >> 16) & 1)) >> 16);
        o.y = (unsigned short)((u[1] + 0x7FFFu + ((u[1] >> 16) & 1)) >> 16);
        o.z = (unsigned short)((u[2] + 0x7FFFu + ((u[2] >> 16) & 1)) >> 16);
        o.w = (unsigned short)((u[3] + 0x7FFFu + ((u[3] >> 16) & 1)) >> 16);
        ((ushort4*)out)[i] = o;
    }
}

// ---------- Phase A: gi[t][row] = W_ih @ x_t + b_ih (+ b_hh for r/z rows) ----------
// b_hh for gate rows [0,512) is folded in here (r/z gates use gi+hh+b_hh
// additively); the n-gate's b_hh stays in k_gru (it sits inside the r* term).
__global__ __launch_bounds__(256) void k_gi(const int* __restrict__ toks,
                                            const float* __restrict__ emb,
                                            const float* __restrict__ W,
                                            const float* __restrict__ b,
                                            const float* __restrict__ bhh,
                                            float* __restrict__ gi, int do_relu) {
    __shared__ float4 xs[64];
    int t = blockIdx.x;
    int tid = threadIdx.x;
    int tok = toks[t];
    if (tid < 64) {
        float4 x = ((const float4*)(emb + (size_t)tok * HDIM))[tid];
        if (do_relu) {
            x.x = fmaxf(x.x, 0.0f); x.y = fmaxf(x.y, 0.0f);
            x.z = fmaxf(x.z, 0.0f); x.w = fmaxf(x.w, 0.0f);
        }
        xs[tid] = x;
    }
    __syncthreads();
#pragma unroll
    for (int g = 0; g < 3; ++g) {
        int row = tid + g * 256;
        const float4* wr = (const float4*)(W + (size_t)row * HDIM);
        float acc = b[row] + ((g < 2) ? bhh[row] : 0.0f);
#pragma unroll 16
        for (int k = 0; k < 64; ++k) {
            float4 w = wr[k];
            float4 x = xs[k];
            acc += w.x * x.x + w.y * x.y + w.z * x.z + w.w * x.w;
        }
        gi[(size_t)t * 768 + row] = acc;
    }
}

// ---------- Phase B: sequential double-GRU ----------
// 512 threads = 8 waves, waves_per_eu pinned to (2,2) => firm 256-VGPR arch
// budget so the 192 weight dwords stay in ARCH VGPRs (no v_accvgpr_read tax).
// Lane: quad q = tid>>2 owns elements {2q, 2q+1}; c = tid&3 is the K-chunk
// (64 h elems = 4 int4 LDS reads -> halves LDS return traffic vs L=2).
// Each lane computes 6 partial rows (2 elems x 3 gates); DPP xor1
// reduce-scatter by element + xor2 butterfly leaves element 2q+(c&1) complete.
// Raw lgkmcnt-only barriers: gi prefetches / h_bf stores never drain.
__global__ __launch_bounds__(512)
__attribute__((amdgpu_waves_per_eu(2, 2))) void k_gru(
    const int* __restrict__ wq_e, const float* __restrict__ sc_e,
    const float* __restrict__ bhh_e, const float* __restrict__ gi_e,
    const int* __restrict__ wq_d, const float* __restrict__ sc_d,
    const float* __restrict__ bhh_d, const float* __restrict__ gi_d,
    unsigned short* __restrict__ h_bf) {
    __shared__ __align__(16) int HQA[64];  // input to encoder half
    __shared__ __align__(16) int HQB[64];  // input to decoder half

    const int tid = threadIdx.x;
    const int q  = tid >> 2;       // quad id [0,128)
    const int c  = tid & 3;        // K-chunk [0,4): h elems [c*64, c*64+64)
    const int el = c & 1;          // element this lane finishes: e = 2q+el
    const int e  = 2 * q + el;
    const bool wr = (c & 2) == 0;  // c in {0,1}: the writer lanes

    // weights: 6 rows x 16 dwords per matrix; p/f order j = el*3 + gate
    int we[6][16], wd[6][16];
#pragma unroll
    for (int eo = 0; eo < 2; ++eo) {
#pragma unroll
        for (int g = 0; g < 3; ++g) {
            const int row = 2 * q + eo + 256 * g;
            const int4* pe = (const int4*)(wq_e + (row * 64 + c * 16));
            const int4* pd = (const int4*)(wq_d + (row * 64 + c * 16));
#pragma unroll
            for (int i = 0; i < 4; ++i) {
                int4 a = pe[i];
                we[eo * 3 + g][4 * i + 0] = a.x; we[eo * 3 + g][4 * i + 1] = a.y;
                we[eo * 3 + g][4 * i + 2] = a.z; we[eo * 3 + g][4 * i + 3] = a.w;
                int4 bq = pd[i];
                wd[eo * 3 + g][4 * i + 0] = bq.x; wd[eo * 3 + g][4 * i + 1] = bq.y;
                wd[eo * 3 + g][4 * i + 2] = bq.z; wd[eo * 3 + g][4 * i + 3] = bq.w;
            }
        }
    }
    // scales for the element this lane finishes; n-gate hh-bias only
    float se0 = sc_e[e] * (1.0f / 127.0f);
    float se1 = sc_e[e + 256] * (1.0f / 127.0f);
    float se2 = sc_e[e + 512] * (1.0f / 127.0f);
    float sd0 = sc_d[e] * (1.0f / 127.0f);
    float sd1 = sc_d[e + 256] * (1.0f / 127.0f);
    float sd2 = sc_d[e + 512] * (1.0f / 127.0f);
    float be2 = bhh_e[e + 512];
    float bd2 = bhh_d[e + 512];

    float h = 0.0f;
    if (tid < 64) HQA[tid] = 0;
    __syncthreads();

    const float* ge = gi_e + e;
    const float* gd = gi_d + e;
    unsigned short* hop = h_bf + e;

    // prologue prefetch: encoder gi of step 0
    float eg0 = ge[0], eg1 = ge[256], eg2 = ge[512];

    for (int t = 0; t < T_STEPS; ++t) {
        // prefetch decoder gi of THIS step (consumed ~a half-step from now)
        float dg0 = gd[0], dg1 = gd[256], dg2 = gd[512];
        gd += 768;

        // ---- encoder half: HQA -> HQB ----
        {
            const int4* hq4 = ((const int4*)HQA) + c * 4;
            int p[6] = {0, 0, 0, 0, 0, 0};
#pragma unroll
            for (int i = 0; i < 4; ++i) {
                int4 v = hq4[i];
#pragma unroll
                for (int j = 0; j < 6; ++j) {
                    p[j] = dot4i8(we[j][4 * i + 0], v.x, p[j]);
                    p[j] = dot4i8(we[j][4 * i + 1], v.y, p[j]);
                    p[j] = dot4i8(we[j][4 * i + 2], v.z, p[j]);
                    p[j] = dot4i8(we[j][4 * i + 3], v.w, p[j]);
                }
            }
            // reduce: xor1 scatter by element, xor2 butterfly
            int f0 = xor1_add(el ? p[3] : p[0], el ? p[0] : p[3]);
            int f1 = xor1_add(el ? p[4] : p[1], el ? p[1] : p[4]);
            int f2 = xor1_add(el ? p[5] : p[2], el ? p[2] : p[5]);
            f0 = xor2_sum(f0); f1 = xor2_sum(f1); f2 = xor2_sum(f2);
            float r = fast_sigmoid(eg0 + se0 * (float)f0);
            float z = fast_sigmoid(eg1 + se1 * (float)f1);
            float n = fast_tanh(eg2 + r * (se2 * (float)f2 + be2));
            h = (1.0f - z) * n + z * h;
            if (wr)
                ((signed char*)HQB)[e] = (signed char)__float2int_rn(h * 127.0f);
        }
        barrier_lds();

        // prefetch encoder gi of NEXT step (consumed a full step from now).
        // Last iteration: clamp back inside gi_e (values unused).
        {
            const float* gen = (t < T_STEPS - 1) ? (ge + 768) : (gi_e + e);
            eg0 = gen[0]; eg1 = gen[256]; eg2 = gen[512];
            ge = gen;
        }

        // ---- decoder half: HQB -> HQA ----
        {
            const int4* hq4 = ((const int4*)HQB) + c * 4;
            int p[6] = {0, 0, 0, 0, 0, 0};
#pragma unroll
            for (int i = 0; i < 4; ++i) {
                int4 v = hq4[i];
#pragma unroll
                for (int j = 0; j < 6; ++j) {
                    p[j] = dot4i8(wd[j][4 * i + 0], v.x, p[j]);
                    p[j] = dot4i8(wd[j][4 * i + 1], v.y, p[j]);
                    p[j] = dot4i8(wd[j][4 * i + 2], v.z, p[j]);
                    p[j] = dot4i8(wd[j][4 * i + 3], v.w, p[j]);
                }
            }
            int f0 = xor1_add(el ? p[3] : p[0], el ? p[0] : p[3]);
            int f1 = xor1_add(el ? p[4] : p[1], el ? p[1] : p[4]);
            int f2 = xor1_add(el ? p[5] : p[2], el ? p[2] : p[5]);
            f0 = xor2_sum(f0); f1 = xor2_sum(f1); f2 = xor2_sum(f2);
            float r = fast_sigmoid(dg0 + sd0 * (float)f0);
            float z = fast_sigmoid(dg1 + sd1 * (float)f1);
            float n = fast_tanh(dg2 + r * (sd2 * (float)f2 + bd2));
            h = (1.0f - z) * n + z * h;
            if (wr) {
                ((signed char*)HQA)[e] = (signed char)__float2int_rn(h * 127.0f);
                unsigned int u = __float_as_uint(h);
                *hop = (unsigned short)((u + 0x7FFFu + ((u >> 16) & 1)) >> 16);
            }
            hop += 256;
        }
        barrier_lds();
    }
}

// ---------- Phase C1: logits = H(2048x256) @ out_W^T + b via bf16 MFMA ----------
__global__ __launch_bounds__(256) void k_logits(const unsigned short* __restrict__ hb,
                                                const unsigned short* __restrict__ wb,
                                                const float* __restrict__ out_b,
                                                float* __restrict__ out) {
    const int vb = blockIdx.x * 64;
    const int tb = blockIdx.y * 64;
    const int w = threadIdx.x >> 6;
    const int l = threadIdx.x & 63;
    const int m = l & 15;
    const int q = l >> 4;

    const unsigned short* aptr = hb + (size_t)(tb + w * 16 + m) * HDIM + q * 8;
    const unsigned short* bptr = wb + (size_t)(vb + m) * HDIM + q * 8;

    short8 af[8];
#pragma unroll
    for (int kt = 0; kt < 8; ++kt) af[kt] = *(const short8*)(aptr + kt * 32);

    f32x4 acc[4];
#pragma unroll
    for (int nt = 0; nt < 4; ++nt)
#pragma unroll
        for (int r = 0; r < 4; ++r) acc[nt][r] = 0.0f;

#pragma unroll
    for (int nt = 0; nt < 4; ++nt) {
        const unsigned short* bp = bptr + (size_t)nt * 16 * HDIM;
#pragma unroll
        for (int kt = 0; kt < 8; ++kt) {
            short8 bf = *(const short8*)(bp + kt * 32);
            acc[nt] = __builtin_amdgcn_mfma_f32_16x16x32_bf16(af[kt], bf, acc[nt], 0, 0, 0);
        }
    }
#pragma unroll
    for (int nt = 0; nt < 4; ++nt) {
        float bias = out_b[vb + nt * 16 + m];
#pragma unroll
        for (int r = 0; r < 4; ++r) {
            out[(size_t)(tb + w * 16 + q * 4 + r) * VOUT + vb + nt * 16 + m] =
                acc[nt][r] + bias;
        }
    }
}

// ---------- Phase C2+C3 fused: per-row logsumexp then subtract ----------
__global__ __launch_bounds__(256) void k_lsesub(float* __restrict__ out) {
    const int t = blockIdx.x;
    const int tid = threadIdx.x;
    float* rowp = out + (size_t)t * VOUT;
    float m = -3.0e38f, l = 0.0f;
    for (int v = tid; v < VOUT; v += 256) {
        float x = rowp[v];
        float M = fmaxf(m, x);
        l = l * __expf(m - M) + __expf(x - M);
        m = M;
    }
#pragma unroll
    for (int off = 32; off; off >>= 1) {
        float m2 = __shfl_xor(m, off);
        float l2 = __shfl_xor(l, off);
        float M = fmaxf(m, m2);
        l = l * __expf(m - M) + l2 * __expf(m2 - M);
        m = M;
    }
    __shared__ float sm[4], sl[4];
    __shared__ float s_lse;
    int lane = tid & 63, wv = tid >> 6;
    if (lane == 0) { sm[wv] = m; sl[wv] = l; }
    __syncthreads();
    if (tid == 0) {
        float M = fmaxf(fmaxf(sm[0], sm[1]), fmaxf(sm[2], sm[3]));
        float L = sl[0] * __expf(sm[0] - M) + sl[1] * __expf(sm[1] - M) +
                  sl[2] * __expf(sm[2] - M) + sl[3] * __expf(sm[3] - M);
        s_lse = M + __logf(L);
    }
    __syncthreads();
    float s = s_lse;
    float4* p4 = (float4*)rowp;
    for (int i = tid; i < VOUT / 4; i += 256) {
        float4 o = p4[i];
        o.x -= s; o.y -= s; o.z -= s; o.w -= s;
        p4[i] = o;
    }
}

extern "C" void kernel_launch(void* const* d_in, const int* in_sizes, int n_in,
                              void* d_out, int out_size, void* d_ws, size_t ws_size,
                              hipStream_t stream) {
    (void)in_sizes; (void)n_in; (void)out_size; (void)ws_size;
    const int*   src      = (const int*)d_in[0];
    const int*   trg      = (const int*)d_in[1];
    const float* enc_emb  = (const float*)d_in[2];
    const float* enc_W_ih = (const float*)d_in[3];
    const float* enc_W_hh = (const float*)d_in[4];
    const float* enc_b_ih = (const float*)d_in[5];
    const float* enc_b_hh = (const float*)d_in[6];
    const float* dec_emb  = (const float*)d_in[7];
    const float* dec_W_ih = (const float*)d_in[8];
    const float* dec_W_hh = (const float*)d_in[9];
    const float* dec_b_ih = (const float*)d_in[10];
    const float* dec_b_hh = (const float*)d_in[11];
    const float* out_W    = (const float*)d_in[12];
    const float* out_b    = (const float*)d_in[13];
    float* out = (float*)d_out;

    char* ws = (char*)d_ws;
    float* gi_e  = (float*)ws; ws += (size_t)T_STEPS * 768 * 4;
    float* gi_d  = (float*)ws; ws += (size_t)T_STEPS * 768 * 4;
    float* sc_e  = (float*)ws; ws += 768 * 4;
    float* sc_d  = (float*)ws; ws += 768 * 4;
    int*   wq_e  = (int*)ws;   ws += 768 * 64 * 4;
    int*   wq_d  = (int*)ws;   ws += 768 * 64 * 4;
    unsigned short* h_bf = (unsigned short*)ws; ws += (size_t)T_STEPS * HDIM * 2;
    unsigned short* w_bf = (unsigned short*)ws; ws += (size_t)VOUT * HDIM * 2;

    k_quant<<<768, 64, 0, stream>>>(enc_W_hh, wq_e, sc_e);
    k_quant<<<768, 64, 0, stream>>>(dec_W_hh, wq_d, sc_d);
    k_cvt<<<(VOUT * HDIM / 4 + 255) / 256, 256, 0, stream>>>(out_W, w_bf, VOUT * HDIM / 4);
    k_gi<<<T_STEPS, 256, 0, stream>>>(src, enc_emb, enc_W_ih, enc_b_ih, enc_b_hh, gi_e, 0);
    k_gi<<<T_STEPS, 256, 0, stream>>>(trg, dec_emb, dec_W_ih, dec_b_ih, dec_b_hh, gi_d, 1);
    k_gru<<<1, 512, 0, stream>>>(wq_e, sc_e, enc_b_hh, gi_e,
                                 wq_d, sc_d, dec_b_hh, gi_d, h_bf);
    k_logits<<<dim3(VOUT / 64, T_STEPS / 64), 256, 0, stream>>>(h_bf, w_bf, out_b, out);
    k_lsesub<<<T_STEPS, 256, 0, stream>>>(out);
}